// Round 2
// baseline (458.764 us; speedup 1.0000x reference)
//
#include <hip/hip_runtime.h>
#include <hip/hip_bf16.h>

// MSAttention collapses: out = sum_n V (attention weights row-normalize to 1 and
// m/n are independently-summed einsum indices). Only V-halves of kv weights used.
//
// out0[b,p,c] = (bsum4(x0) @ WvPeer0)[b,p/4,c] + (bsum2(x1) @ WvKid0)[b,p,c]
// out1[b,p,c] = (bsum2(x1)@WvPeer1 + x0@WvPar1)[b,p/2,c] + (bsum2(x2)@WvKid1)[b,p,c]
// out2[b,p,c] = (bsum2(x2)@WvPeer2 + x1@WvPar2)[b,p/2,c]
//
// WvX = rows 256..511 of the [512,256] kv weight (V half), out channel c = row 256+c.
// Output dtype: float32 (reference returns f32; harness d_out follows ref dtype).

constexpr int FD = 256;  // feature dim

// S[b,bh,bw,c] = sum over hb x hb block of x
__global__ __launch_bounds__(256) void blocksum_kernel(
    const float* __restrict__ x, float* __restrict__ S, int Hs, int Ws, int hb) {
  int row = blockIdx.x;          // (b*Hs + bh)*Ws + bw
  int c = threadIdx.x;
  int bw = row % Ws;
  int t2 = row / Ws;
  int bh = t2 % Hs;
  int b = t2 / Hs;
  int W = Ws * hb;
  int H = Hs * hb;
  const float* xb =
      x + ((((size_t)b * H) + (size_t)bh * hb) * W + (size_t)bw * hb) * FD + c;
  float s = 0.f;
  for (int i = 0; i < hb; ++i)
    for (int j = 0; j < hb; ++j) s += xb[((size_t)i * W + j) * FD];
  S[(size_t)row * FD + c] = s;
}

// C[r,c] = sum_d Aa[r,d]*Wa[256+c,d] (+ Ab[r,d]*Wb[256+c,d] if DUAL)
// scattered/broadcast UPxUP into out (f32), = or += per ADD.
// Block: 256 threads = 256 out channels; 16 rows per block.
template <int UP, bool ADD, bool DUAL>
__global__ __launch_bounds__(256) void gemm_scatter(
    const float4* __restrict__ Aa, const float4* __restrict__ Wa_,
    const float4* __restrict__ Ab, const float4* __restrict__ Wb_,
    float* __restrict__ out, int Ha, int Wc) {
  int t = threadIdx.x;
  int row0 = blockIdx.x * 16;
  const float4* wra = Wa_ + (size_t)(FD + t) * 64;
  const float4* wrb = DUAL ? (Wb_ + (size_t)(FD + t) * 64) : nullptr;
  float acc[16];
#pragma unroll
  for (int r = 0; r < 16; ++r) acc[r] = 0.f;
  for (int ch = 0; ch < 64; ++ch) {
    float4 w = wra[ch];
#pragma unroll
    for (int r = 0; r < 16; ++r) {
      // uniform address (blockIdx/loop derived) -> scalar loads, L1/L2 resident
      float4 a = Aa[(size_t)(row0 + r) * 64 + ch];
      acc[r] += a.x * w.x + a.y * w.y + a.z * w.z + a.w * w.w;
    }
    if (DUAL) {
      float4 w2 = wrb[ch];
#pragma unroll
      for (int r = 0; r < 16; ++r) {
        float4 a = Ab[(size_t)(row0 + r) * 64 + ch];
        acc[r] += a.x * w2.x + a.y * w2.y + a.z * w2.z + a.w * w2.w;
      }
    }
  }
  int Ho = Ha * UP, Wo = Wc * UP;
#pragma unroll
  for (int r = 0; r < 16; ++r) {
    int rg = row0 + r;
    int aw = rg % Wc;
    int tmp = rg / Wc;
    int ah = tmp % Ha;
    int b = tmp / Ha;
    for (int i = 0; i < UP; ++i)
      for (int j = 0; j < UP; ++j) {
        size_t o =
            (((size_t)b * Ho + (ah * UP + i)) * Wo + (aw * UP + j)) * FD + t;
        if (ADD)
          out[o] += acc[r];
        else
          out[o] = acc[r];
      }
  }
}

extern "C" void kernel_launch(void* const* d_in, const int* in_sizes, int n_in,
                              void* d_out, int out_size, void* d_ws,
                              size_t ws_size, hipStream_t stream) {
  const float* x0 = (const float*)d_in[0];  // [8,16,16,256]
  const float* x1 = (const float*)d_in[1];  // [8,32,32,256]
  const float* x2 = (const float*)d_in[2];  // [8,64,64,256]

  // kv weights: detect dict order (q/kv interleaved) vs signature order.
  const float *kvpeer0, *kvpeer1, *kvpeer2, *kvpar1, *kvpar2, *kvkid0, *kvkid1;
  if (n_in > 4 && in_sizes[4] == 2 * FD * FD) {
    // setup_inputs() dict order: 3 qpeer0,4 kvpeer0,5 qpeer1,6 kvpeer1,
    // 7 qpeer2,8 kvpeer2,9 qpar1,10 kvpar1,11 qpar2,12 kvpar2,
    // 13 qkid0,14 kvkid0,15 qkid1,16 kvkid1
    kvpeer0 = (const float*)d_in[4];
    kvpeer1 = (const float*)d_in[6];
    kvpeer2 = (const float*)d_in[8];
    kvpar1 = (const float*)d_in[10];
    kvpar2 = (const float*)d_in[12];
    kvkid0 = (const float*)d_in[14];
    kvkid1 = (const float*)d_in[16];
  } else {
    // reference() signature order
    kvpeer0 = (const float*)d_in[6];
    kvpeer1 = (const float*)d_in[7];
    kvpeer2 = (const float*)d_in[8];
    kvpar1 = (const float*)d_in[11];
    kvpar2 = (const float*)d_in[12];
    kvkid0 = (const float*)d_in[15];
    kvkid1 = (const float*)d_in[16];
  }

  float* S0 = (float*)d_ws;        // [8,4,4,256]   = 32768 f
  float* S1 = S0 + 128 * FD;       // [8,16,16,256] = 524288 f
  float* S2 = S1 + 2048 * FD;      // [8,32,32,256] = 2097152 f  (total ~10.1 MB)

  float* out0 = (float*)d_out;
  float* out1 = out0 + (size_t)8 * 16 * 16 * FD;
  float* out2 = out1 + (size_t)8 * 32 * 32 * FD;

  blocksum_kernel<<<128, 256, 0, stream>>>(x0, S0, 4, 4, 4);
  blocksum_kernel<<<2048, 256, 0, stream>>>(x1, S1, 16, 16, 2);
  blocksum_kernel<<<8192, 256, 0, stream>>>(x2, S2, 32, 32, 2);

  // out0 = up4(S0 @ WvPeer0) + S1 @ WvKid0
  gemm_scatter<4, false, false><<<8, 256, 0, stream>>>(
      (const float4*)S0, (const float4*)kvpeer0, nullptr, nullptr, out0, 4, 4);
  gemm_scatter<1, true, false><<<128, 256, 0, stream>>>(
      (const float4*)S1, (const float4*)kvkid0, nullptr, nullptr, out0, 16, 16);

  // out1 = up2(S1 @ WvPeer1 + x0 @ WvPar1) + S2 @ WvKid1
  gemm_scatter<2, false, true><<<128, 256, 0, stream>>>(
      (const float4*)S1, (const float4*)kvpeer1, (const float4*)x0,
      (const float4*)kvpar1, out1, 16, 16);
  gemm_scatter<1, true, false><<<512, 256, 0, stream>>>(
      (const float4*)S2, (const float4*)kvkid1, nullptr, nullptr, out1, 32, 32);

  // out2 = up2(S2 @ WvPeer2 + x1 @ WvPar2)
  gemm_scatter<2, false, true><<<512, 256, 0, stream>>>(
      (const float4*)S2, (const float4*)kvpeer2, (const float4*)x1,
      (const float4*)kvpar2, out2, 32, 32);
}

// Round 3
// 401.591 us; speedup vs baseline: 1.1424x; 1.1424x over previous
//
#include <hip/hip_runtime.h>

// MSAttention collapses: out = sum_n V (attention rows normalize to 1; m,n are
// independently summed einsum indices). Only V-halves (rows 256..511) of kv
// weights matter, and value block-sums commute with the linear projection:
//   out0 = up4(S0 @ Wpeer0) + S1 @ Wkid0
//   out1 = up2(S1 @ Wpeer1 + x0 @ Wpar1) + S2 @ Wkid1
//   out2 = up2(S2 @ Wpeer2 + x1 @ Wpar2)
// where Sk = 2x2 (4x4 for S0) spatial block-sum of xk. Output dtype f32.

constexpr int FD = 256;
constexpr int F4 = FD / 4;  // float4 per row

// One launch computes S0, S1, S2. Block handles 4 rows x 64 float4-channels.
__global__ __launch_bounds__(256) void blocksum_all(
    const float4* __restrict__ x0, const float4* __restrict__ x1,
    const float4* __restrict__ x2, float4* __restrict__ S0,
    float4* __restrict__ S1, float4* __restrict__ S2) {
  int blk = blockIdx.x;
  const float4* x;
  float4* S;
  int Hs, Ws, hb, row0;
  if (blk < 32) {
    x = x0; S = S0; Hs = 4; Ws = 4; hb = 4; row0 = blk * 4;
  } else if (blk < 32 + 512) {
    x = x1; S = S1; Hs = 16; Ws = 16; hb = 2; row0 = (blk - 32) * 4;
  } else {
    x = x2; S = S2; Hs = 32; Ws = 32; hb = 2; row0 = (blk - 544) * 4;
  }
  int t = threadIdx.x;
  int c = t & 63;
  int row = row0 + (t >> 6);
  int bw = row % Ws;
  int t2 = row / Ws;
  int bh = t2 % Hs;
  int b = t2 / Hs;
  int W = Ws * hb;
  const float4* xb = x + (((size_t)b * Hs * hb + bh * hb) * W + bw * hb) * F4 + c;
  float4 s = {0.f, 0.f, 0.f, 0.f};
  for (int i = 0; i < hb; ++i)
    for (int j = 0; j < hb; ++j) {
      float4 v = xb[((size_t)i * W + j) * F4];
      s.x += v.x; s.y += v.y; s.z += v.z; s.w += v.w;
    }
  S[(size_t)row * F4 + c] = s;
}

// out0 coarse: up4 broadcast of S0 @ Wpeer0. 128 rows, 1 row/block.
__global__ __launch_bounds__(256) void gemm_up4(
    const float4* __restrict__ S0, const float4* __restrict__ W,
    float* __restrict__ out0) {
  int t = threadIdx.x;
  int row = blockIdx.x;  // (b*4+ah)*4+aw
  const float4* wr = W + (size_t)(FD + t) * F4;
  const float4* ar = S0 + (size_t)row * F4;
  float acc = 0.f;
#pragma unroll 8
  for (int ch = 0; ch < F4; ++ch) {
    float4 w = wr[ch];
    float4 a = ar[ch];
    acc += a.x * w.x + a.y * w.y + a.z * w.z + a.w * w.w;
  }
  int aw = row & 3;
  int ah = (row >> 2) & 3;
  int b = row >> 4;
  for (int i = 0; i < 4; ++i)
    for (int j = 0; j < 4; ++j)
      out0[(((size_t)b * 16 + ah * 4 + i) * 16 + aw * 4 + j) * FD + t] = acc;
}

// Fused per-S-row kernel: for each row r of S (grid [B,Ha,Wa]):
//   outK[r] += S[r] @ Wkid            (kid term of the coarser scale, UP=1)
//   outC[2x2 of r] = S[r]@Wpeer + X[r]@Wpar   (this scale's coarse term, UP=2)
template <int R>
__global__ __launch_bounds__(256) void fused_gemm(
    const float4* __restrict__ S, const float4* __restrict__ X,
    const float4* __restrict__ Wkid, const float4* __restrict__ Wpeer,
    const float4* __restrict__ Wpar, float* __restrict__ outK,
    float* __restrict__ outC, int Ha, int Wa) {
  int t = threadIdx.x;
  int row0 = blockIdx.x * R;
  const float4* wk = Wkid + (size_t)(FD + t) * F4;
  const float4* wp = Wpeer + (size_t)(FD + t) * F4;
  const float4* wq = Wpar + (size_t)(FD + t) * F4;
  float accK[R], accC[R];
#pragma unroll
  for (int r = 0; r < R; ++r) {
    accK[r] = 0.f;
    accC[r] = 0.f;
  }
#pragma unroll 4
  for (int ch = 0; ch < F4; ++ch) {
    float4 k4 = wk[ch], p4 = wp[ch], q4 = wq[ch];
#pragma unroll
    for (int r = 0; r < R; ++r) {
      // uniform (blockIdx/loop-derived) addresses -> scalar loads
      float4 a = S[(size_t)(row0 + r) * F4 + ch];
      accK[r] += a.x * k4.x + a.y * k4.y + a.z * k4.z + a.w * k4.w;
      accC[r] += a.x * p4.x + a.y * p4.y + a.z * p4.z + a.w * p4.w;
      float4 b = X[(size_t)(row0 + r) * F4 + ch];
      accC[r] += b.x * q4.x + b.y * q4.y + b.z * q4.z + b.w * q4.w;
    }
  }
  int Wo = Wa * 2;
#pragma unroll
  for (int r = 0; r < R; ++r) {
    int rg = row0 + r;
    int aw = rg % Wa;
    int tmp = rg / Wa;
    int ah = tmp % Ha;
    int b = tmp / Ha;
    outK[(size_t)rg * FD + t] += accK[r];
    size_t o = (((size_t)b * Ha * 2 + ah * 2) * Wo + aw * 2) * FD + t;
    outC[o] = accC[r];
    outC[o + FD] = accC[r];
    outC[o + (size_t)Wo * FD] = accC[r];
    outC[o + (size_t)Wo * FD + FD] = accC[r];
  }
}

extern "C" void kernel_launch(void* const* d_in, const int* in_sizes, int n_in,
                              void* d_out, int out_size, void* d_ws,
                              size_t ws_size, hipStream_t stream) {
  const float* x0 = (const float*)d_in[0];  // [8,16,16,256]
  const float* x1 = (const float*)d_in[1];  // [8,32,32,256]
  const float* x2 = (const float*)d_in[2];  // [8,64,64,256]

  // kv weights: detect dict order (q/kv interleaved) vs signature order.
  const float *kvpeer0, *kvpeer1, *kvpeer2, *kvpar1, *kvpar2, *kvkid0, *kvkid1;
  if (n_in > 4 && in_sizes[4] == 2 * FD * FD) {
    kvpeer0 = (const float*)d_in[4];
    kvpeer1 = (const float*)d_in[6];
    kvpeer2 = (const float*)d_in[8];
    kvpar1 = (const float*)d_in[10];
    kvpar2 = (const float*)d_in[12];
    kvkid0 = (const float*)d_in[14];
    kvkid1 = (const float*)d_in[16];
  } else {
    kvpeer0 = (const float*)d_in[6];
    kvpeer1 = (const float*)d_in[7];
    kvpeer2 = (const float*)d_in[8];
    kvpar1 = (const float*)d_in[11];
    kvpar2 = (const float*)d_in[12];
    kvkid0 = (const float*)d_in[15];
    kvkid1 = (const float*)d_in[16];
  }

  float* S0 = (float*)d_ws;     // [8,4,4,256]
  float* S1 = S0 + 128 * FD;    // [8,16,16,256]
  float* S2 = S1 + 2048 * FD;   // [8,32,32,256]

  float* out0 = (float*)d_out;
  float* out1 = out0 + (size_t)8 * 16 * 16 * FD;
  float* out2 = out1 + (size_t)8 * 32 * 32 * FD;

  // S0:32 blocks, S1:512, S2:2048
  blocksum_all<<<2592, 256, 0, stream>>>(
      (const float4*)x0, (const float4*)x1, (const float4*)x2, (float4*)S0,
      (float4*)S1, (float4*)S2);

  // out0 coarse (must precede fused S1 kernel's += into out0)
  gemm_up4<<<128, 256, 0, stream>>>((const float4*)S0, (const float4*)kvpeer0,
                                    out0);

  // S1 rows: kid0 -> out0 (+=), peer1+par1(x0) -> out1 (=, up2). 2048 rows.
  fused_gemm<4><<<512, 256, 0, stream>>>(
      (const float4*)S1, (const float4*)x0, (const float4*)kvkid0,
      (const float4*)kvpeer1, (const float4*)kvpar1, out0, out1, 16, 16);

  // S2 rows: kid1 -> out1 (+=), peer2+par2(x1) -> out2 (=, up2). 8192 rows.
  fused_gemm<8><<<1024, 256, 0, stream>>>(
      (const float4*)S2, (const float4*)x1, (const float4*)kvkid1,
      (const float4*)kvpeer2, (const float4*)kvpar2, out1, out2, 32, 32);
}

// Round 4
// 174.542 us; speedup vs baseline: 2.6284x; 2.3008x over previous
//
#include <hip/hip_runtime.h>

// MSAttention collapses: out = sum_n V (attention rows normalize to 1; m,n are
// independently summed einsum indices). Only V-halves (rows 256..511) of kv
// weights matter, and value block-sums commute with the linear projection:
//   out0 = up4(S0 @ Wpeer0) + S1 @ Wkid0
//   out1 = up2(S1 @ Wpeer1 + x0 @ Wpar1) + S2 @ Wkid1
//   out2 = up2(S2 @ Wpeer2 + x1 @ Wpar2)
// Sk = 2x2 (4x4 for S0) spatial block-sum of xk. Output f32.
// GEMMs via v_mfma_f32_16x16x32_bf16; A/B frags are contiguous 16B loads.

constexpr int FD = 256;

typedef __attribute__((ext_vector_type(8))) short short8;   // 8 bf16
typedef __attribute__((ext_vector_type(4))) float floatx4;  // C/D frag

__device__ inline unsigned short bf16bits(float f) {
  unsigned u = __builtin_bit_cast(unsigned, f);
  return (unsigned short)((u + 0x7fffu + ((u >> 16) & 1u)) >> 16);
}

// load 8 consecutive f32, round-to-nearest-even to bf16 frag
__device__ inline short8 load_cvt8(const float* p) {
  float4 a = *(const float4*)p;
  float4 b = *(const float4*)(p + 4);
  short8 r;
  r[0] = (short)bf16bits(a.x); r[1] = (short)bf16bits(a.y);
  r[2] = (short)bf16bits(a.z); r[3] = (short)bf16bits(a.w);
  r[4] = (short)bf16bits(b.x); r[5] = (short)bf16bits(b.y);
  r[6] = (short)bf16bits(b.z); r[7] = (short)bf16bits(b.w);
  return r;
}

// ws layout (bf16 elements):
//   S0b: [144,256] (128 valid rows + pad for A-frag overread)
//   S1b: [2048,256]   S2b: [8192,256]
//   Wb : 7 x [256,256]  order: peer0,kid0,peer1,par1,kid1,peer2,par2
constexpr size_t OFF_S1 = 144 * 256;
constexpr size_t OFF_S2 = OFF_S1 + 2048 * 256;
constexpr size_t OFF_W = OFF_S2 + 8192 * 256;

// K1: blocksums (f32 in, bf16 out) + V-half weight conversion.
__global__ __launch_bounds__(256) void prep(
    const float4* __restrict__ x0, const float4* __restrict__ x1,
    const float4* __restrict__ x2, const float* __restrict__ wp0,
    const float* __restrict__ wk0, const float* __restrict__ wp1,
    const float* __restrict__ wq1, const float* __restrict__ wk1,
    const float* __restrict__ wp2, const float* __restrict__ wq2,
    unsigned short* __restrict__ ws) {
  int blk = blockIdx.x;
  int t = threadIdx.x;
  if (blk < 2592) {  // block sums: 4 rows x 64 float4-channels
    const float4* x;
    unsigned short* S;
    int Hs, Ws, hb, row0;
    if (blk < 32) {
      x = x0; S = ws; Hs = 4; Ws = 4; hb = 4; row0 = blk * 4;
    } else if (blk < 544) {
      x = x1; S = ws + OFF_S1; Hs = 16; Ws = 16; hb = 2; row0 = (blk - 32) * 4;
    } else {
      x = x2; S = ws + OFF_S2; Hs = 32; Ws = 32; hb = 2; row0 = (blk - 544) * 4;
    }
    int c = t & 63;
    int row = row0 + (t >> 6);
    int bw = row % Ws;
    int t2 = row / Ws;
    int bh = t2 % Hs;
    int b = t2 / Hs;
    int W = Ws * hb;
    const float4* xb =
        x + (((size_t)b * Hs * hb + bh * hb) * W + bw * hb) * 64 + c;
    float4 s = {0.f, 0.f, 0.f, 0.f};
    for (int i = 0; i < hb; ++i)
      for (int j = 0; j < hb; ++j) {
        float4 v = xb[((size_t)i * W + j) * 64];
        s.x += v.x; s.y += v.y; s.z += v.z; s.w += v.w;
      }
    ushort4 o = {bf16bits(s.x), bf16bits(s.y), bf16bits(s.z), bf16bits(s.w)};
    *(ushort4*)(S + (size_t)row * FD + c * 4) = o;
  } else {  // weight cvt: 7 mats x 64 groups of 4 rows
    int wb = blk - 2592;
    int mat = wb >> 6;
    int row = (wb & 63) * 4 + (t >> 6);
    int c4 = (t & 63) * 4;
    const float* src;
    switch (mat) {
      case 0: src = wp0; break;
      case 1: src = wk0; break;
      case 2: src = wp1; break;
      case 3: src = wq1; break;
      case 4: src = wk1; break;
      case 5: src = wp2; break;
      default: src = wq2; break;
    }
    float4 v = *(const float4*)(src + (size_t)(256 + row) * FD + c4);
    ushort4 o = {bf16bits(v.x), bf16bits(v.y), bf16bits(v.z), bf16bits(v.w)};
    *(ushort4*)(ws + OFF_W + (size_t)mat * 65536 + (size_t)row * FD + c4) = o;
  }
}

#define MFMA(a, b, c) __builtin_amdgcn_mfma_f32_16x16x32_bf16(a, b, c, 0, 0, 0)

// K2: blocks [0,128): out0 = S1@Wkid0 + up4(S0@Wpeer0)   (fused per block)
//     blocks [128,256): out1 = up2(S1@Wpeer1 + cvt(x0)@Wpar1)
__global__ __launch_bounds__(256) void gemm12(
    const unsigned short* __restrict__ ws, const float* __restrict__ x0,
    float* __restrict__ out0, float* __restrict__ out1) {
  bool segB = blockIdx.x >= 128;
  int bid = segB ? blockIdx.x - 128 : blockIdx.x;
  int r0 = (bid >> 2) * 64;
  int n0 = (bid & 3) * 64;
  int l = threadIdx.x & 63;
  int wv = threadIdx.x >> 6;
  int c = l & 15, q = l >> 4;
  int n = n0 + wv * 16 + c;
  const short8* S1b = (const short8*)(ws + OFF_S1);
  const short8* Wb = (const short8*)(ws + OFF_W);
  const short8* aS[4];
#pragma unroll
  for (int mt = 0; mt < 4; ++mt)
    aS[mt] = S1b + (size_t)(r0 + mt * 16 + c) * 32 + q;

  if (!segB) {
    const short8* aC = (const short8*)ws + (size_t)((r0 >> 4) + c) * 32 + q;
    const short8* bK = Wb + (size_t)1 * 8192 + n * 32 + q;  // kid0
    const short8* bP = Wb + (size_t)0 * 8192 + n * 32 + q;  // peer0
    floatx4 accK[4] = {0, 0, 0, 0};
    floatx4 accC = {0, 0, 0, 0};
#pragma unroll 2
    for (int kk = 0; kk < 8; ++kk) {
      short8 b0 = bK[kk * 4];
      short8 b1 = bP[kk * 4];
#pragma unroll
      for (int mt = 0; mt < 4; ++mt) accK[mt] = MFMA(aS[mt][kk * 4], b0, accK[mt]);
      accC = MFMA(aC[kk * 4], b1, accC);
    }
    // coarse value for this lane: C-row q of lane c (only rows 0..3 valid/used)
    float s0 = __shfl(accC[0], c), s1 = __shfl(accC[1], c);
    float s2 = __shfl(accC[2], c), s3 = __shfl(accC[3], c);
    float cv = q == 0 ? s0 : q == 1 ? s1 : q == 2 ? s2 : s3;
#pragma unroll
    for (int mt = 0; mt < 4; ++mt)
#pragma unroll
      for (int r = 0; r < 4; ++r) {
        int row = r0 + mt * 16 + 4 * q + r;
        out0[(size_t)row * FD + n] = accK[mt][r] + cv;
      }
  } else {
    const float* aX[4];
#pragma unroll
    for (int mt = 0; mt < 4; ++mt)
      aX[mt] = x0 + (size_t)(r0 + mt * 16 + c) * FD + q * 8;
    const short8* bP = Wb + (size_t)2 * 8192 + n * 32 + q;  // peer1
    const short8* bQ = Wb + (size_t)3 * 8192 + n * 32 + q;  // par1
    floatx4 acc[4] = {0, 0, 0, 0};
#pragma unroll 2
    for (int kk = 0; kk < 8; ++kk) {
      short8 b0 = bP[kk * 4];
      short8 b1 = bQ[kk * 4];
#pragma unroll
      for (int mt = 0; mt < 4; ++mt) {
        acc[mt] = MFMA(aS[mt][kk * 4], b0, acc[mt]);
        acc[mt] = MFMA(load_cvt8(aX[mt] + kk * 32), b1, acc[mt]);
      }
    }
#pragma unroll
    for (int mt = 0; mt < 4; ++mt)
#pragma unroll
      for (int r = 0; r < 4; ++r) {
        int rg = r0 + mt * 16 + 4 * q + r;  // S1 row (b,h,w) in 16-grid
        int b = rg >> 8, h = (rg >> 4) & 15, w = rg & 15;
        size_t o = ((size_t)b * 1024 + h * 64 + 2 * w) * FD + n;
        float v = acc[mt][r];
        out1[o] = v;
        out1[o + FD] = v;
        out1[o + 8192] = v;
        out1[o + 8192 + FD] = v;
      }
  }
}

// K3: per 64 S2-rows: out1 += S2@Wkid1 ; out2 = up2(S2@Wpeer2 + cvt(x1)@Wpar2)
__global__ __launch_bounds__(256) void gemm3(
    const unsigned short* __restrict__ ws, const float* __restrict__ x1,
    float* __restrict__ out1, float* __restrict__ out2) {
  int r0 = (blockIdx.x >> 2) * 64;
  int n0 = (blockIdx.x & 3) * 64;
  int l = threadIdx.x & 63;
  int wv = threadIdx.x >> 6;
  int c = l & 15, q = l >> 4;
  int n = n0 + wv * 16 + c;
  const short8* S2b = (const short8*)(ws + OFF_S2);
  const short8* Wb = (const short8*)(ws + OFF_W);
  const short8* aS[4];
  const float* aX[4];
#pragma unroll
  for (int mt = 0; mt < 4; ++mt) {
    aS[mt] = S2b + (size_t)(r0 + mt * 16 + c) * 32 + q;
    aX[mt] = x1 + (size_t)(r0 + mt * 16 + c) * FD + q * 8;
  }
  const short8* bK = Wb + (size_t)4 * 8192 + n * 32 + q;  // kid1
  const short8* bP = Wb + (size_t)5 * 8192 + n * 32 + q;  // peer2
  const short8* bQ = Wb + (size_t)6 * 8192 + n * 32 + q;  // par2
  floatx4 accK[4] = {0, 0, 0, 0};
  floatx4 accC[4] = {0, 0, 0, 0};
#pragma unroll 2
  for (int kk = 0; kk < 8; ++kk) {
    short8 b0 = bK[kk * 4];
    short8 b1 = bP[kk * 4];
    short8 b2 = bQ[kk * 4];
#pragma unroll
    for (int mt = 0; mt < 4; ++mt) {
      short8 a = aS[mt][kk * 4];
      accK[mt] = MFMA(a, b0, accK[mt]);
      accC[mt] = MFMA(a, b1, accC[mt]);
      accC[mt] = MFMA(load_cvt8(aX[mt] + kk * 32), b2, accC[mt]);
    }
  }
#pragma unroll
  for (int mt = 0; mt < 4; ++mt)
#pragma unroll
    for (int r = 0; r < 4; ++r) {
      int rg = r0 + mt * 16 + 4 * q + r;  // S2 row == out1 row index
      size_t o1 = (size_t)rg * FD + n;
      out1[o1] += accK[mt][r];
      int b = rg >> 10, h = (rg >> 5) & 31, w = rg & 31;
      size_t o = ((size_t)b * 4096 + h * 128 + 2 * w) * FD + n;
      float v = accC[mt][r];
      out2[o] = v;
      out2[o + FD] = v;
      out2[o + 16384] = v;
      out2[o + 16384 + FD] = v;
    }
}

extern "C" void kernel_launch(void* const* d_in, const int* in_sizes, int n_in,
                              void* d_out, int out_size, void* d_ws,
                              size_t ws_size, hipStream_t stream) {
  const float* x0 = (const float*)d_in[0];  // [8,16,16,256]
  const float* x1 = (const float*)d_in[1];  // [8,32,32,256]
  const float* x2 = (const float*)d_in[2];  // [8,64,64,256]

  const float *kvpeer0, *kvpeer1, *kvpeer2, *kvpar1, *kvpar2, *kvkid0, *kvkid1;
  if (n_in > 4 && in_sizes[4] == 2 * FD * FD) {  // setup_inputs dict order
    kvpeer0 = (const float*)d_in[4];
    kvpeer1 = (const float*)d_in[6];
    kvpeer2 = (const float*)d_in[8];
    kvpar1 = (const float*)d_in[10];
    kvpar2 = (const float*)d_in[12];
    kvkid0 = (const float*)d_in[14];
    kvkid1 = (const float*)d_in[16];
  } else {  // reference() signature order
    kvpeer0 = (const float*)d_in[6];
    kvpeer1 = (const float*)d_in[7];
    kvpeer2 = (const float*)d_in[8];
    kvpar1 = (const float*)d_in[11];
    kvpar2 = (const float*)d_in[12];
    kvkid0 = (const float*)d_in[15];
    kvkid1 = (const float*)d_in[16];
  }

  unsigned short* ws = (unsigned short*)d_ws;  // ~6.0 MB bf16 scratch
  float* out0 = (float*)d_out;
  float* out1 = out0 + (size_t)8 * 16 * 16 * FD;
  float* out2 = out1 + (size_t)8 * 32 * 32 * FD;

  prep<<<3040, 256, 0, stream>>>((const float4*)x0, (const float4*)x1,
                                 (const float4*)x2, kvpeer0, kvkid0, kvpeer1,
                                 kvpar1, kvkid1, kvpeer2, kvpar2, ws);
  gemm12<<<256, 256, 0, stream>>>(ws, x0, out0, out1);
  gemm3<<<512, 256, 0, stream>>>(ws, x1, out1, out2);
}

// Round 5
// 167.703 us; speedup vs baseline: 2.7356x; 1.0408x over previous
//
#include <hip/hip_runtime.h>

// MSAttention collapses: out = sum_n V (attention rows normalize to 1; m,n are
// independently summed einsum indices). Only V-halves (rows 256..511) of kv
// weights matter; value block-sums commute with the linear projection:
//   out0 = S1 @ Wkid0 + up4(S0 @ Wpeer0)
//   out1 = S2 @ Wkid1 + up2(S1 @ Wpeer1 + x0 @ Wpar1)
//   out2 =              up2(S2 @ Wpeer2 + x1 @ Wpar2)
// Sk = 2x2 (4x4 for S0) spatial block-sum of xk. Output f32.
// All GEMMs via v_mfma_f32_16x16x32_bf16. out1's coarse term is computed in
// the same block as its kid term (64-row tiles need exactly 16 contiguous S1
// coarse rows) -> no read-modify-write on out1.

constexpr int FD = 256;

typedef __attribute__((ext_vector_type(8))) short short8;   // 8 bf16
typedef __attribute__((ext_vector_type(4))) float floatx4;  // C/D frag

__device__ inline unsigned short bf16bits(float f) {
  unsigned u = __builtin_bit_cast(unsigned, f);
  return (unsigned short)((u + 0x7fffu + ((u >> 16) & 1u)) >> 16);
}
__device__ inline ushort4 cvt4(float4 v) {
  ushort4 o;
  o.x = bf16bits(v.x); o.y = bf16bits(v.y);
  o.z = bf16bits(v.z); o.w = bf16bits(v.w);
  return o;
}

// ws layout (bf16 elements):
//   S0b [144,256] (128 valid + pad)   S1b [2048,256]   S2b [8192,256]
//   Wb 7x[256,256]: peer0,kid0,peer1,par1,kid1,peer2,par2
//   x0b [2048,256]   x1b [8192,256]
constexpr size_t OFF_S1 = 144 * 256;
constexpr size_t OFF_S2 = OFF_S1 + 2048 * 256;
constexpr size_t OFF_W = OFF_S2 + 8192 * 256;
constexpr size_t OFF_X0 = OFF_W + 7 * 65536;
constexpr size_t OFF_X1 = OFF_X0 + 2048 * 256;  // end: 5738496 el = 11.5 MB

// K1: blocksums (f32->bf16) + bf16 copies of x0,x1 + V-half weight cvt.
__global__ __launch_bounds__(256) void prep(
    const float4* __restrict__ x0, const float4* __restrict__ x1,
    const float4* __restrict__ x2, const float* __restrict__ wp0,
    const float* __restrict__ wk0, const float* __restrict__ wp1,
    const float* __restrict__ wq1, const float* __restrict__ wk1,
    const float* __restrict__ wp2, const float* __restrict__ wq2,
    unsigned short* __restrict__ ws) {
  int blk = blockIdx.x;
  int t = threadIdx.x;
  if (blk < 2592) {  // block sums: 4 rows x 64 float4-channels
    const float4* x;
    unsigned short* S;
    unsigned short* xo = nullptr;
    int Hs, Ws, hb, row0;
    if (blk < 32) {
      x = x0; S = ws; xo = ws + OFF_X0; Hs = 4; Ws = 4; hb = 4; row0 = blk * 4;
    } else if (blk < 544) {
      x = x1; S = ws + OFF_S1; xo = ws + OFF_X1;
      Hs = 16; Ws = 16; hb = 2; row0 = (blk - 32) * 4;
    } else {
      x = x2; S = ws + OFF_S2; Hs = 32; Ws = 32; hb = 2; row0 = (blk - 544) * 4;
    }
    int c = t & 63;
    int row = row0 + (t >> 6);
    int bw = row % Ws;
    int t2 = row / Ws;
    int bh = t2 % Hs;
    int b = t2 / Hs;
    int W = Ws * hb;
    size_t base4 = (((size_t)b * Hs * hb + bh * hb) * W + bw * hb) * 64 + c;
    const float4* xb = x + base4;
    float4 s = {0.f, 0.f, 0.f, 0.f};
    for (int i = 0; i < hb; ++i)
      for (int j = 0; j < hb; ++j) {
        float4 v = xb[(size_t)(i * W + j) * 64];
        s.x += v.x; s.y += v.y; s.z += v.z; s.w += v.w;
        if (xo) *(ushort4*)(xo + (base4 + (size_t)(i * W + j) * 64) * 4) = cvt4(v);
      }
    *(ushort4*)(S + (size_t)row * FD + c * 4) = cvt4(s);
  } else {  // weight cvt: 7 mats x 64 groups of 4 rows (V half = rows 256..511)
    int wb = blk - 2592;
    int mat = wb >> 6;
    int row = (wb & 63) * 4 + (t >> 6);
    int c4 = (t & 63) * 4;
    const float* src;
    switch (mat) {
      case 0: src = wp0; break;
      case 1: src = wk0; break;
      case 2: src = wp1; break;
      case 3: src = wq1; break;
      case 4: src = wk1; break;
      case 5: src = wp2; break;
      default: src = wq2; break;
    }
    float4 v = *(const float4*)(src + (size_t)(256 + row) * FD + c4);
    *(ushort4*)(ws + OFF_W + (size_t)mat * 65536 + (size_t)row * FD + c4) =
        cvt4(v);
  }
}

#define MFMA(a, b, c) __builtin_amdgcn_mfma_f32_16x16x32_bf16(a, b, c, 0, 0, 0)

// K2: blocks [0,512): out1 = S2@Wk1 + up2(S1@Wp1 + x0b@Wq1)  and
//                     out2 = up2(S2@Wp2 + x1b@Wq2)           (64 rows x 64 cols)
//     blocks [512,640): out0 = S1@Wk0 + up4(S0@Wp0)
__global__ __launch_bounds__(256) void gemm(const unsigned short* __restrict__ ws,
                                            float* __restrict__ out0,
                                            float* __restrict__ out1,
                                            float* __restrict__ out2) {
  __shared__ float lds[4][16][17];  // per-wave 16x16 coarse tile, padded
  int t = threadIdx.x;
  int l = t & 63;
  int wv = t >> 6;
  int c = l & 15, q = l >> 4;
  const short8* Wb = (const short8*)(ws + OFF_W);

  if (blockIdx.x < 512) {
    int r0 = (blockIdx.x >> 2) * 64;   // S2-row tile (== out1 row tile)
    int n0 = (blockIdx.x & 3) * 64;
    int n = n0 + wv * 16 + c;
    const short8* S2b = (const short8*)(ws + OFF_S2);
    const short8* X1b = (const short8*)(ws + OFF_X1);
    // coarse S1/x0 rows: b*256 + (h/2)*16, 16 contiguous rows (h even)
    int cb0 = (r0 >> 10) * 256 + (((r0 >> 5) & 31) >> 1) * 16;
    const short8* aS1 = (const short8*)(ws + OFF_S1) + (size_t)(cb0 + c) * 32 + q;
    const short8* aX0 = (const short8*)(ws + OFF_X0) + (size_t)(cb0 + c) * 32 + q;
    const short8 *aS2[4], *aX1[4];
#pragma unroll
    for (int mt = 0; mt < 4; ++mt) {
      aS2[mt] = S2b + (size_t)(r0 + mt * 16 + c) * 32 + q;
      aX1[mt] = X1b + (size_t)(r0 + mt * 16 + c) * 32 + q;
    }
    const short8* bK1 = Wb + (size_t)4 * 8192 + (size_t)n * 32 + q;
    const short8* bP2 = Wb + (size_t)5 * 8192 + (size_t)n * 32 + q;
    const short8* bQ2 = Wb + (size_t)6 * 8192 + (size_t)n * 32 + q;
    const short8* bP1 = Wb + (size_t)2 * 8192 + (size_t)n * 32 + q;
    const short8* bQ1 = Wb + (size_t)3 * 8192 + (size_t)n * 32 + q;
    floatx4 accK[4] = {0, 0, 0, 0};
    floatx4 accC2[4] = {0, 0, 0, 0};
    floatx4 accC1 = {0, 0, 0, 0};
#pragma unroll 2
    for (int kk = 0; kk < 8; ++kk) {
      short8 k1 = bK1[kk * 4], p2 = bP2[kk * 4], q2 = bQ2[kk * 4];
      short8 p1 = bP1[kk * 4], q1 = bQ1[kk * 4];
      accC1 = MFMA(aS1[kk * 4], p1, accC1);
      accC1 = MFMA(aX0[kk * 4], q1, accC1);
#pragma unroll
      for (int mt = 0; mt < 4; ++mt) {
        short8 a = aS2[mt][kk * 4];
        accK[mt] = MFMA(a, k1, accK[mt]);
        accC2[mt] = MFMA(a, p2, accC2[mt]);
        accC2[mt] = MFMA(aX1[mt][kk * 4], q2, accC2[mt]);
      }
    }
    // coarse tile -> LDS (row = w1, col = c), then up2 gather
#pragma unroll
    for (int r = 0; r < 4; ++r) lds[wv][4 * q + r][c] = accC1[r];
    __syncthreads();
#pragma unroll
    for (int mt = 0; mt < 4; ++mt)
#pragma unroll
      for (int r = 0; r < 4; ++r) {
        int rg = r0 + mt * 16 + 4 * q + r;
        int w = rg & 31;
        out1[(size_t)rg * FD + n] = accK[mt][r] + lds[wv][w >> 1][c];
        int b = rg >> 10, h = (rg >> 5) & 31;
        size_t o = ((size_t)b * 4096 + h * 128 + 2 * w) * FD + n;
        float v = accC2[mt][r];
        out2[o] = v;
        out2[o + FD] = v;
        out2[o + 16384] = v;
        out2[o + 16384 + FD] = v;
      }
  } else {
    int bid = blockIdx.x - 512;
    int r0 = (bid >> 2) * 64;  // S1-row tile (== out0 row tile)
    int n0 = (bid & 3) * 64;
    int n = n0 + wv * 16 + c;
    const short8* S1b = (const short8*)(ws + OFF_S1);
    const short8* aC = (const short8*)ws + (size_t)((r0 >> 4) + c) * 32 + q;
    const short8* bK = Wb + (size_t)1 * 8192 + (size_t)n * 32 + q;  // kid0
    const short8* bP = Wb + (size_t)0 * 8192 + (size_t)n * 32 + q;  // peer0
    const short8* aS[4];
#pragma unroll
    for (int mt = 0; mt < 4; ++mt)
      aS[mt] = S1b + (size_t)(r0 + mt * 16 + c) * 32 + q;
    floatx4 accK[4] = {0, 0, 0, 0};
    floatx4 accC = {0, 0, 0, 0};
#pragma unroll 2
    for (int kk = 0; kk < 8; ++kk) {
      short8 b0 = bK[kk * 4], b1 = bP[kk * 4];
      accC = MFMA(aC[kk * 4], b1, accC);
#pragma unroll
      for (int mt = 0; mt < 4; ++mt) accK[mt] = MFMA(aS[mt][kk * 4], b0, accK[mt]);
    }
    // up4: out row needs S0 row (r0>>4)+q -> C-tile row q, col c
    float s0 = __shfl(accC[0], c), s1 = __shfl(accC[1], c);
    float s2 = __shfl(accC[2], c), s3 = __shfl(accC[3], c);
    float cv = q == 0 ? s0 : q == 1 ? s1 : q == 2 ? s2 : s3;
#pragma unroll
    for (int mt = 0; mt < 4; ++mt)
#pragma unroll
      for (int r = 0; r < 4; ++r)
        out0[(size_t)(r0 + mt * 16 + 4 * q + r) * FD + n] = accK[mt][r] + cv;
  }
}

extern "C" void kernel_launch(void* const* d_in, const int* in_sizes, int n_in,
                              void* d_out, int out_size, void* d_ws,
                              size_t ws_size, hipStream_t stream) {
  const float* x0 = (const float*)d_in[0];  // [8,16,16,256]
  const float* x1 = (const float*)d_in[1];  // [8,32,32,256]
  const float* x2 = (const float*)d_in[2];  // [8,64,64,256]

  const float *kvpeer0, *kvpeer1, *kvpeer2, *kvpar1, *kvpar2, *kvkid0, *kvkid1;
  if (n_in > 4 && in_sizes[4] == 2 * FD * FD) {  // setup_inputs dict order
    kvpeer0 = (const float*)d_in[4];
    kvpeer1 = (const float*)d_in[6];
    kvpeer2 = (const float*)d_in[8];
    kvpar1 = (const float*)d_in[10];
    kvpar2 = (const float*)d_in[12];
    kvkid0 = (const float*)d_in[14];
    kvkid1 = (const float*)d_in[16];
  } else {  // reference() signature order
    kvpeer0 = (const float*)d_in[6];
    kvpeer1 = (const float*)d_in[7];
    kvpeer2 = (const float*)d_in[8];
    kvpar1 = (const float*)d_in[11];
    kvpar2 = (const float*)d_in[12];
    kvkid0 = (const float*)d_in[15];
    kvkid1 = (const float*)d_in[16];
  }

  unsigned short* ws = (unsigned short*)d_ws;  // ~11.5 MB bf16 scratch
  float* out0 = (float*)d_out;
  float* out1 = out0 + (size_t)8 * 16 * 16 * FD;
  float* out2 = out1 + (size_t)8 * 32 * 32 * FD;

  prep<<<3040, 256, 0, stream>>>((const float4*)x0, (const float4*)x1,
                                 (const float4*)x2, kvpeer0, kvkid0, kvpeer1,
                                 kvpar1, kvkid1, kvpeer2, kvpar2, ws);
  gemm<<<640, 256, 0, stream>>>(ws, out0, out1, out2);
}